// Round 2
// baseline (8426.897 us; speedup 1.0000x reference)
//
#include <hip/hip_runtime.h>
#include <math.h>

#define B_  16
#define T_  128
#define N_  50
#define D_  512
#define KH  8
#define DH  64
#define M_TOK (B_*T_*N_)   // 102400

// ---------------------------------------------------------------------------
// Generic fp32 tiled GEMM:  C = act(A @ W + bias)
//   a_mode==0: plain contiguous A (lda = K)
//   a_mode==1: A = concat([X (512), TLE (1024)], axis=-1), K must be 1536
//   W is (K x 512) row-major, C is (M x 512).
//   Tile: BM=128, BN=128, BK=8; 256 threads; 8x8 micro-tile per thread.
// ---------------------------------------------------------------------------
__global__ __launch_bounds__(256) void gemm_kernel(
    const float* __restrict__ A,
    const float* __restrict__ X,
    const float* __restrict__ TLE,
    const float* __restrict__ W,
    const float* __restrict__ bias,
    float* __restrict__ C,
    int K, int do_relu, int a_mode)
{
    __shared__ __align__(16) float As[8][132];  // [k][m]
    __shared__ __align__(16) float Bs[8][132];  // [k][n]

    const int tid = threadIdx.x;
    const int tx  = tid & 15;        // 16 cols of 8 -> 128
    const int ty  = tid >> 4;        // 16 rows of 8 -> 128
    const int n0  = blockIdx.x * 128;
    const int m0  = blockIdx.y * 128;

    float acc[8][8];
    #pragma unroll
    for (int i = 0; i < 8; ++i)
        #pragma unroll
        for (int j = 0; j < 8; ++j) acc[i][j] = 0.f;

    // staging indices
    const int a_row = tid >> 1;            // 0..127
    const int a_k4  = (tid & 1) * 4;       // 0 or 4
    const int b_k   = tid >> 5;            // 0..7
    const int b_n4  = (tid & 31) * 4;      // 0..124

    for (int k0 = 0; k0 < K; k0 += 8) {
        // ---- stage A tile (128 x 8), one float4 per thread ----
        {
            const int row = m0 + a_row;
            const float* src;
            if (a_mode == 1) {
                const int kk = k0 + a_k4;
                src = (kk < 512) ? (X   + (size_t)row * 512  + kk)
                                 : (TLE + (size_t)row * 1024 + (kk - 512));
            } else {
                src = A + (size_t)row * K + k0 + a_k4;
            }
            float4 av = *(const float4*)src;
            As[a_k4 + 0][a_row] = av.x;
            As[a_k4 + 1][a_row] = av.y;
            As[a_k4 + 2][a_row] = av.z;
            As[a_k4 + 3][a_row] = av.w;
        }
        // ---- stage B tile (8 x 128), one float4 per thread ----
        {
            float4 bv4 = *(const float4*)(W + (size_t)(k0 + b_k) * 512 + n0 + b_n4);
            *(float4*)&Bs[b_k][b_n4] = bv4;
        }
        __syncthreads();

        #pragma unroll
        for (int kk = 0; kk < 8; ++kk) {
            float4 a0 = *(const float4*)&As[kk][ty * 8];
            float4 a1 = *(const float4*)&As[kk][ty * 8 + 4];
            float4 b0 = *(const float4*)&Bs[kk][tx * 8];
            float4 b1 = *(const float4*)&Bs[kk][tx * 8 + 4];
            float a[8] = {a0.x, a0.y, a0.z, a0.w, a1.x, a1.y, a1.z, a1.w};
            float b[8] = {b0.x, b0.y, b0.z, b0.w, b1.x, b1.y, b1.z, b1.w};
            #pragma unroll
            for (int i = 0; i < 8; ++i)
                #pragma unroll
                for (int j = 0; j < 8; ++j)
                    acc[i][j] = fmaf(a[i], b[j], acc[i][j]);
        }
        __syncthreads();
    }

    // ---- epilogue: bias (+ relu), float4 stores ----
    float bb[8];
    #pragma unroll
    for (int j = 0; j < 8; ++j) bb[j] = bias[n0 + tx * 8 + j];

    #pragma unroll
    for (int i = 0; i < 8; ++i) {
        const int row = m0 + ty * 8 + i;
        float* cp = C + (size_t)row * 512 + n0 + tx * 8;
        #pragma unroll
        for (int j = 0; j < 8; ++j) {
            float v = acc[i][j] + bb[j];
            if (do_relu) v = fmaxf(v, 0.f);
            acc[i][j] = v;
        }
        *(float4*)cp       = make_float4(acc[i][0], acc[i][1], acc[i][2], acc[i][3]);
        *(float4*)(cp + 4) = make_float4(acc[i][4], acc[i][5], acc[i][6], acc[i][7]);
    }
}

// ---------------------------------------------------------------------------
// Attention: one block per (b_local, n, h). 128 threads, one per query row t.
// Two-pass softmax (recompute dots); LDS = k-tile + v-tile = 64 KB.
// Writes attn output IN PLACE over the q buffer.
// q/k/v point at the CURRENT CHUNK's buffers; kpm is pre-offset to the chunk.
// ---------------------------------------------------------------------------
__global__ __launch_bounds__(128) void attn_kernel(
    float* __restrict__ q,
    const float* __restrict__ k,
    const float* __restrict__ v,
    const int* __restrict__ kpm)
{
    __shared__ __align__(16) float ks[T_ * DH];   // 32 KB
    __shared__ __align__(16) float vs[T_ * DH];   // 32 KB

    const int h = blockIdx.x;
    const int n = blockIdx.y;
    const int b = blockIdx.z;    // local to chunk
    const int tid = threadIdx.x;

    const size_t tstride = (size_t)N_ * D_;                    // 25600
    const size_t base = ((size_t)b * T_ * N_ + n) * D_ + (size_t)h * DH;

    // stage k and v tiles (128 x 64 each)
    for (int idx = tid; idx < T_ * (DH / 4); idx += 128) {
        const int row = idx >> 4;
        const int d4  = (idx & 15) * 4;
        *(float4*)&ks[row * DH + d4] = *(const float4*)(k + base + row * tstride + d4);
        *(float4*)&vs[row * DH + d4] = *(const float4*)(v + base + row * tstride + d4);
    }

    // this thread's query row
    const int t = tid;
    float qr[DH];
    {
        const float* qp = q + base + t * tstride;
        #pragma unroll
        for (int d4 = 0; d4 < DH; d4 += 4)
            *(float4*)&qr[d4] = *(const float4*)(qp + d4);
    }
    __syncthreads();

    const int L    = kpm[b];
    const int pmax = min(t + 1, L);   // valid keys: [0, pmax), pmax >= 1

    // pass 1: row max
    float m = -1e30f;
    for (int p = 0; p < pmax; ++p) {
        const float* kp = &ks[p * DH];
        float acc = 0.f;
        #pragma unroll
        for (int d = 0; d < DH; ++d) acc = fmaf(qr[d], kp[d], acc);
        m = fmaxf(m, acc * 0.125f);
    }

    // pass 2: exp + weighted accumulation of v
    float out[DH];
    #pragma unroll
    for (int d = 0; d < DH; ++d) out[d] = 0.f;
    float sum = 0.f;
    for (int p = 0; p < pmax; ++p) {
        const float* kp = &ks[p * DH];
        float acc = 0.f;
        #pragma unroll
        for (int d = 0; d < DH; ++d) acc = fmaf(qr[d], kp[d], acc);
        const float e = __expf(acc * 0.125f - m);
        sum += e;
        const float* vp = &vs[p * DH];
        #pragma unroll
        for (int d = 0; d < DH; ++d) out[d] = fmaf(e, vp[d], out[d]);
    }
    const float inv = 1.0f / sum;

    float* op = q + base + t * tstride;
    #pragma unroll
    for (int d4 = 0; d4 < DH; d4 += 4) {
        float4 o = make_float4(out[d4] * inv, out[d4+1] * inv,
                               out[d4+2] * inv, out[d4+3] * inv);
        *(float4*)(op + d4) = o;
    }
}

// ---------------------------------------------------------------------------
// Host: chunk the whole (batch-separable) pipeline over B so that the three
// fp32 scratch buffers fit in ws_size. chunk_B=16 needs ~630 MB; each halving
// halves that. Work is bit-identical regardless of chunking.
// ---------------------------------------------------------------------------
extern "C" void kernel_launch(void* const* d_in, const int* in_sizes, int n_in,
                              void* d_out, int out_size, void* d_ws, size_t ws_size,
                              hipStream_t stream)
{
    const float* X   = (const float*)d_in[0];
    const float* TLE = (const float*)d_in[1];
    const int*   kpm = (const int*)  d_in[2];
    const float* Wq  = (const float*)d_in[3];
    const float* bq  = (const float*)d_in[4];
    const float* Wk  = (const float*)d_in[5];
    const float* bk  = (const float*)d_in[6];
    const float* Wv  = (const float*)d_in[7];
    const float* bv  = (const float*)d_in[8];
    const float* W1  = (const float*)d_in[9];
    const float* b1  = (const float*)d_in[10];
    const float* W2  = (const float*)d_in[11];
    const float* b2  = (const float*)d_in[12];
    float* out = (float*)d_out;

    // pick largest chunk_B whose 3 fp32 buffers fit in ws_size
    int chunk_B = 16;
    while (chunk_B > 1 &&
           (size_t)3 * chunk_B * T_ * N_ * D_ * sizeof(float) > ws_size)
        chunk_B >>= 1;

    const size_t rows_per_b = (size_t)T_ * N_;          // 6400
    const dim3 gemm_block(256);

    for (int b0 = 0; b0 < B_; b0 += chunk_B) {
        const int cb = chunk_B;
        const size_t row0   = (size_t)b0 * rows_per_b;
        const size_t crows  = (size_t)cb * rows_per_b;   // chunk M
        const size_t bufsz  = crows * D_;

        float* qb = (float*)d_ws;
        float* kb = qb + bufsz;
        float* vb = kb + bufsz;

        const dim3 gemm_grid(D_ / 128, (unsigned)(crows / 128));

        const float* Xc   = X   + row0 * 512;
        const float* TLEc = TLE + row0 * 1024;

        // QKV projections: relu(H @ W + b), H = concat(X, TLE)
        gemm_kernel<<<gemm_grid, gemm_block, 0, stream>>>(nullptr, Xc, TLEc, Wq, bq, qb, 1536, 1, 1);
        gemm_kernel<<<gemm_grid, gemm_block, 0, stream>>>(nullptr, Xc, TLEc, Wk, bk, kb, 1536, 1, 1);
        gemm_kernel<<<gemm_grid, gemm_block, 0, stream>>>(nullptr, Xc, TLEc, Wv, bv, vb, 1536, 1, 1);

        // attention (in-place over qb)
        attn_kernel<<<dim3(KH, N_, cb), dim3(128), 0, stream>>>(qb, kb, vb, kpm + b0);

        // FFN: relu(attn_out @ W1 + b1) -> kb ; kb @ W2 + b2 -> out chunk
        gemm_kernel<<<gemm_grid, gemm_block, 0, stream>>>(qb, nullptr, nullptr, W1, b1, kb, 512, 1, 0);
        gemm_kernel<<<gemm_grid, gemm_block, 0, stream>>>(kb, nullptr, nullptr, W2, b2,
                                                          out + row0 * D_, 512, 0, 0);
    }
}